// Round 7
// baseline (878.404 us; speedup 1.0000x reference)
//
#include <hip/hip_runtime.h>
#include <math.h>

#define N_NODES   50000
#define N_EDGES   800000
#define BASIS     64
#define HIDDEN_RO 128
#define N_GRAPHS  512
#define T_ITERS   3
#define NB_SCAN   ((N_NODES + 255) / 256)   // 196

typedef short s8 __attribute__((ext_vector_type(8)));   // 8 bf16 in 4 VGPRs
typedef float f4 __attribute__((ext_vector_type(4)));

#define MFMA16(a, b, c) __builtin_amdgcn_mfma_f32_16x16x32_bf16(a, b, c, 0, 0, 0)

// tanh(x) = 1 - 2/(e^{2x}+1); overflow-safe both directions, tanh(0)=0 exactly.
__device__ __forceinline__ float fast_tanh(float x) {
    float e = __expf(2.0f * x);
    return 1.0f - 2.0f / (e + 1.0f);
}

__device__ __forceinline__ f4 splat4(float x) { f4 v; v[0]=x; v[1]=x; v[2]=x; v[3]=x; return v; }

// Split 8 fp32 into bf16 hi (truncation) + bf16 lo (residual) — proven, absmax 0.0625.
__device__ __forceinline__ void split8(const float* x, s8& hi, s8& lo) {
    union { unsigned a[4]; s8 v; } H, L;
    #pragma unroll
    for (int j = 0; j < 4; ++j) {
        float e0 = x[2*j], e1 = x[2*j+1];
        unsigned u0 = __float_as_uint(e0), u1 = __float_as_uint(e1);
        H.a[j] = (u0 >> 16) | (u1 & 0xFFFF0000u);
        float l0 = e0 - __uint_as_float(u0 & 0xFFFF0000u);   // exact
        float l1 = e1 - __uint_as_float(u1 & 0xFFFF0000u);
        L.a[j] = (__float_as_uint(l0) >> 16) | (__float_as_uint(l1) & 0xFFFF0000u);
    }
    hi = H.v; lo = L.v;
}

// ---- W frag pre-pack: img[f*64+lane], f = ks*4+g (hi), 8+ks*4+g (lo); 16 KB/matrix ----
__device__ __forceinline__ void packW_dev(const float* __restrict__ W, s8* __restrict__ img, int t) {
    int lane = t & 63, q = lane >> 4, c = lane & 15;
    int f0 = (t >> 6) * 2;
    #pragma unroll
    for (int f = f0; f < f0 + 2; ++f) {          // f in 0..7 across the 4 sub-groups
        int ks = f >> 2, g = f & 3;
        float tv[8];
        #pragma unroll
        for (int j = 0; j < 8; ++j)
            tv[j] = W[(ks*32 + q*8 + j) * 64 + g*16 + c];
        s8 hi, lo;
        split8(tv, hi, lo);
        img[f * 64 + lane]       = hi;
        img[(8 + f) * 64 + lane] = lo;
    }
}

// W1 readout pack: 64x128 -> 16 hi frags (f = ks*8+g) + 16 lo frags; 32 KB image
__device__ __forceinline__ void packW1_dev(const float* __restrict__ W, s8* __restrict__ img, int t) {
    int lane = t & 63, q = lane >> 4, c = lane & 15;
    int f0 = (t >> 6) * 4;
    #pragma unroll
    for (int f = f0; f < f0 + 4; ++f) {          // f in 0..15 across the 4 waves
        int ks = f >> 3, g = f & 7;
        float tv[8];
        #pragma unroll
        for (int j = 0; j < 8; ++j)
            tv[j] = W[(ks*32 + q*8 + j) * HIDDEN_RO + g*16 + c];
        s8 hi, lo;
        split8(tv, hi, lo);
        img[f * 64 + lane]        = hi;
        img[(16 + f) * 64 + lane] = lo;
    }
}

__global__ void k_packW(const float* __restrict__ W0, const float* __restrict__ W1m,
                        const float* __restrict__ W2m, const float* __restrict__ W1ro,
                        s8* __restrict__ i0, s8* __restrict__ i1, s8* __restrict__ i2,
                        s8* __restrict__ i3) {
    int b = blockIdx.x, t = threadIdx.x;
    if (b == 0) packW_dev(W0, i0, t);
    else if (b == 1) packW_dev(W1m, i1, t);
    else if (b == 2) packW_dev(W2m, i2, t);
    else packW1_dev(W1ro, i3, t);
}

// C init + degree histogram fused
__global__ void k_init_hist(const int* __restrict__ Z, const float* __restrict__ embed,
                            float* __restrict__ C, const int* __restrict__ dst,
                            int* __restrict__ deg) {
    int i = blockIdx.x * blockDim.x + threadIdx.x;
    if (i < N_NODES * BASIS) { int n = i >> 6, c = i & 63; C[i] = embed[Z[n] * 64 + c]; }
    if (i < N_EDGES) atomicAdd(&deg[dst[i]], 1);
}

// ---- hierarchical scan: 196-block local scan -> 1-block scan of block sums -> add-back ----
__global__ void k_scan1(const int* __restrict__ deg, int* __restrict__ off,
                        int* __restrict__ bsum) {
    __shared__ int ws[4];
    int b = blockIdx.x, t = threadIdx.x, lane = t & 63, w = t >> 6;
    int i = b * 256 + t;
    int v = (i < N_NODES) ? deg[i] : 0;
    int s = v;
    #pragma unroll
    for (int ofs = 1; ofs < 64; ofs <<= 1) {
        int tmp = __shfl_up(s, ofs, 64);
        if (lane >= ofs) s += tmp;
    }
    if (lane == 63) ws[w] = s;
    __syncthreads();
    if (t == 0) {
        int a = 0;
        #pragma unroll
        for (int k = 0; k < 4; ++k) { int x = ws[k]; ws[k] = a; a += x; }
        bsum[b] = a;
    }
    __syncthreads();
    int excl = ws[w] + s - v;
    if (i < N_NODES) off[i] = excl;
}

__global__ void k_scan2(int* __restrict__ bsum) {   // 1 block, 256 threads; NB_SCAN <= 256
    __shared__ int ws[4];
    int t = threadIdx.x, lane = t & 63, w = t >> 6;
    int v = (t < NB_SCAN) ? bsum[t] : 0;
    int s = v;
    #pragma unroll
    for (int ofs = 1; ofs < 64; ofs <<= 1) {
        int tmp = __shfl_up(s, ofs, 64);
        if (lane >= ofs) s += tmp;
    }
    if (lane == 63) ws[w] = s;
    __syncthreads();
    if (t == 0) {
        int a = 0;
        #pragma unroll
        for (int k = 0; k < 4; ++k) { int x = ws[k]; ws[k] = a; a += x; }
    }
    __syncthreads();
    int excl = ws[w] + s - v;
    if (t < NB_SCAN) bsum[t] = excl;
}

__global__ void k_scan3(const int* __restrict__ deg, int* __restrict__ off,
                        const int* __restrict__ bsum, int* __restrict__ cursor) {
    int b = blockIdx.x, i = b * 256 + threadIdx.x;
    if (i < N_NODES) {
        int val = off[i] + bsum[b];
        off[i] = val;
        cursor[i] = val;
        if (i == N_NODES - 1) off[N_NODES] = val + deg[i];
    }
}

// slot_s[p]=src (slot-ordered), slot_p[e]=p (edge->slot inverse permutation)
__global__ void k_fill(const int* __restrict__ src, const int* __restrict__ dst,
                       int* __restrict__ cursor, int* __restrict__ slot_s,
                       int* __restrict__ slot_p) {
    int e = blockIdx.x * blockDim.x + threadIdx.x;
    if (e < N_EDGES) {
        int d = dst[e], s = src[e];
        int p = atomicAdd(&cursor[d], 1);
        slot_s[p] = s;
        slot_p[e] = p;
    }
}

// ---- generic 64x64 linear via MFMA, W frags from LDS ----
// MODE 0: out[r,:] = in[r,:]@W + b, sequential rows in and out.
// MODE 2: out[map[r],:] = in[r,:]@W + b — sequential coalesced READ, scattered write.
template <int MODE>
__global__ __launch_bounds__(256, 4) void k_gemm64L(const float* __restrict__ in,
        const s8* __restrict__ wimg, const float* __restrict__ b,
        const int* __restrict__ map, float* __restrict__ out, int rows) {
    __shared__ s8 LW[1024];   // 16 KB
    int t = threadIdx.x;
    for (int i = t; i < 1024; i += 256) LW[i] = wimg[i];
    __syncthreads();
    int lane = t & 63, wv = t >> 6, q = lane >> 4, c = lane & 15;
    float bias[4];
    #pragma unroll
    for (int g = 0; g < 4; ++g) bias[g] = b[g*16 + c];
    int chunks = (rows + 15) >> 4;
    int wave = blockIdx.x * 4 + wv, nw = gridDim.x * 4;
    for (int ch = wave; ch < chunks; ch += nw) {
        int base = ch << 4;
        int row = base + c;
        bool valid = row < rows;
        int r = valid ? row : 0;
        const float4* ip = (const float4*)(in + (size_t)r * 64);
        s8 ahi[2], alo[2];
        #pragma unroll
        for (int ks = 0; ks < 2; ++ks) {
            float4 a0 = ip[ks*8 + q*2 + 0];
            float4 a1 = ip[ks*8 + q*2 + 1];
            float xs[8] = {a0.x,a0.y,a0.z,a0.w, a1.x,a1.y,a1.z,a1.w};
            if (!valid) {
                #pragma unroll
                for (int j = 0; j < 8; ++j) xs[j] = 0.0f;
            }
            split8(xs, ahi[ks], alo[ks]);
        }
        int orow[4];
        #pragma unroll
        for (int r2 = 0; r2 < 4; ++r2) {
            int ro = base + q*4 + r2;
            if (ro >= rows) ro = rows - 1;
            orow[r2] = (MODE == 2) ? map[ro] : ro;
        }
        f4 acc[4];
        #pragma unroll
        for (int g = 0; g < 4; ++g) acc[g] = splat4(bias[g]);
        #pragma unroll
        for (int ks = 0; ks < 2; ++ks)
            #pragma unroll
            for (int g = 0; g < 4; ++g) {
                s8 wh = LW[(ks*4 + g) * 64 + lane];
                s8 wl = LW[(8 + ks*4 + g) * 64 + lane];
                acc[g] = MFMA16(ahi[ks], wh, acc[g]);
                acc[g] = MFMA16(ahi[ks], wl, acc[g]);
                acc[g] = MFMA16(alo[ks], wh, acc[g]);
            }
        #pragma unroll
        for (int g = 0; g < 4; ++g)
            #pragma unroll
            for (int r2 = 0; r2 < 4; ++r2) {
                if (base + q*4 + r2 < rows)
                    out[(size_t)orow[r2] * 64 + g*16 + c] = acc[g][r2];
            }
    }
}

// ---- fused message+aggregate: R1 structure + 1-ahead DF prefetch ONLY ----
// DF is the HBM stream (195 MB/dispatch, ~600-900 cy); its address is slot-computable,
// so prefetching next chunk's 4 float4 (+16 VGPR, 60->~80, budget 128 at (256,4))
// hides it under the current chunk's CF-load+split+MFMA+tanh. CF is L2/L3-hot, and
// slot_s already prefetches 1-ahead (R1-proven). R2's combined DF+CF+off prefetch
// spilled; this is the surgical subset. Occupancy squeezes are closed (R4/R5 spills).
__global__ __launch_bounds__(256, 4) void k_mp7(const float* __restrict__ CF,
        const float* __restrict__ DF, const s8* __restrict__ wimg,
        const int* __restrict__ slot_s, const int* __restrict__ off,
        float* __restrict__ C) {
    __shared__ s8 LW[1024];   // 16 KB
    int t = threadIdx.x;
    for (int i = t; i < 1024; i += 256) LW[i] = wimg[i];
    __syncthreads();
    int lane = t & 63, wv = t >> 6, q = lane >> 4, c = lane & 15;
    int wave = blockIdx.x * 4 + wv, nw = gridDim.x * 4;
    for (int n = wave; n < N_NODES; n += nw) {
        int beg = off[n], end = off[n + 1];
        if (beg >= end) continue;
        float acc0 = 0.f, acc1 = 0.f, acc2 = 0.f, acc3 = 0.f;
        int sl0 = beg + c; if (sl0 >= end) sl0 = end - 1;
        int srcn = slot_s[sl0];                  // prefetched src for chunk 0
        float4 e0, e1, e2, e3;                   // prefetched DF for chunk 0
        {
            const float4* dp = (const float4*)(DF + (size_t)sl0 * 64);
            e0 = dp[q*2]; e1 = dp[q*2 + 1]; e2 = dp[8 + q*2]; e3 = dp[8 + q*2 + 1];
        }
        #pragma unroll 1
        for (int base = beg; base < end; base += 16) {
            int slot = base + c;
            bool valid = slot < end;
            int scur = srcn;
            float4 d0 = e0, d1 = e1, d2 = e2, d3 = e3;   // consume prefetched DF
            if (base + 16 < end) {               // prefetch next chunk's src + DF
                int s2 = base + 16 + c; if (s2 >= end) s2 = end - 1;
                srcn = slot_s[s2];
                const float4* dp = (const float4*)(DF + (size_t)s2 * 64);
                e0 = dp[q*2]; e1 = dp[q*2 + 1]; e2 = dp[8 + q*2]; e3 = dp[8 + q*2 + 1];
            }
            const float4* cp = (const float4*)(CF + (size_t)scur * 64);  // gather (L2/L3 hot)
            float4 c0 = cp[q*2],     c1 = cp[q*2 + 1];
            float4 c2 = cp[8 + q*2], c3 = cp[8 + q*2 + 1];
            s8 ahi[2], alo[2];
            {
                float xs[8] = {c0.x*d0.x, c0.y*d0.y, c0.z*d0.z, c0.w*d0.w,
                               c1.x*d1.x, c1.y*d1.y, c1.z*d1.z, c1.w*d1.w};
                if (!valid) {
                    #pragma unroll
                    for (int j = 0; j < 8; ++j) xs[j] = 0.0f;
                }
                split8(xs, ahi[0], alo[0]);
                float ys[8] = {c2.x*d2.x, c2.y*d2.y, c2.z*d2.z, c2.w*d2.w,
                               c3.x*d3.x, c3.y*d3.y, c3.z*d3.z, c3.w*d3.w};
                if (!valid) {
                    #pragma unroll
                    for (int j = 0; j < 8; ++j) ys[j] = 0.0f;
                }
                split8(ys, ahi[1], alo[1]);
            }
            f4 d[4];
            #pragma unroll
            for (int g = 0; g < 4; ++g) d[g] = splat4(0.0f);
            #pragma unroll
            for (int ks = 0; ks < 2; ++ks)
                #pragma unroll
                for (int g = 0; g < 4; ++g) {
                    s8 wh = LW[(ks*4 + g) * 64 + lane];
                    s8 wl = LW[(8 + ks*4 + g) * 64 + lane];
                    d[g] = MFMA16(ahi[ks], wh, d[g]);
                    d[g] = MFMA16(ahi[ks], wl, d[g]);
                    d[g] = MFMA16(alo[ks], wh, d[g]);
                }
            // tail rows had zero A -> d=0 -> tanh(0)=0: safe to sum all regs
            acc0 += fast_tanh(d[0][0]) + fast_tanh(d[0][1]) + fast_tanh(d[0][2]) + fast_tanh(d[0][3]);
            acc1 += fast_tanh(d[1][0]) + fast_tanh(d[1][1]) + fast_tanh(d[1][2]) + fast_tanh(d[1][3]);
            acc2 += fast_tanh(d[2][0]) + fast_tanh(d[2][1]) + fast_tanh(d[2][2]) + fast_tanh(d[2][3]);
            acc3 += fast_tanh(d[3][0]) + fast_tanh(d[3][1]) + fast_tanh(d[3][2]) + fast_tanh(d[3][3]);
        }
        // reduce across the 4 lane-quads (edge-row subsets) — verified
        acc0 += __shfl_xor(acc0, 16, 64); acc0 += __shfl_xor(acc0, 32, 64);
        acc1 += __shfl_xor(acc1, 16, 64); acc1 += __shfl_xor(acc1, 32, 64);
        acc2 += __shfl_xor(acc2, 16, 64); acc2 += __shfl_xor(acc2, 32, 64);
        acc3 += __shfl_xor(acc3, 16, 64); acc3 += __shfl_xor(acc3, 32, 64);
        float v = (q == 0) ? acc0 : (q == 1) ? acc1 : (q == 2) ? acc2 : acc3;
        C[(size_t)n * 64 + lane] += v;
    }
}

// ---- fallback path (ws too small; never expected — kept for safety) ----
__global__ __launch_bounds__(256) void k_gemm64_fb(const float* __restrict__ in,
        const float* __restrict__ W, const float* __restrict__ b,
        float* __restrict__ out, int rows) {
    int r = blockIdx.x * blockDim.x + threadIdx.x;
    if (r >= rows) return;
    float acc[BASIS];
    #pragma unroll
    for (int c = 0; c < BASIS; ++c) acc[c] = b[c];
    const float4* in4 = (const float4*)(in + (size_t)r * BASIS);
    #pragma unroll 1
    for (int k0 = 0; k0 < 16; ++k0) {
        float4 xv = in4[k0];
        #pragma unroll
        for (int c = 0; c < BASIS; ++c)
            acc[c] += xv.x * W[(4*k0+0)*64+c] + xv.y * W[(4*k0+1)*64+c]
                    + xv.z * W[(4*k0+2)*64+c] + xv.w * W[(4*k0+3)*64+c];
    }
    #pragma unroll
    for (int c = 0; c < BASIS; ++c) out[(size_t)r * BASIS + c] = acc[c];
}
__global__ __launch_bounds__(256) void k_edge_fb(const float* __restrict__ CF,
        const float* __restrict__ ea, const float* __restrict__ dfW,
        const float* __restrict__ dfb, const float* __restrict__ fcW,
        const int* __restrict__ src, const int* __restrict__ dst,
        float* __restrict__ C) {
    int e = blockIdx.x * blockDim.x + threadIdx.x;
    if (e >= N_EDGES) return;
    int s = src[e], d = dst[e];
    float dfeat[BASIS];
    #pragma unroll
    for (int c = 0; c < BASIS; ++c) dfeat[c] = dfb[c];
    const float4* ea4 = (const float4*)(ea + (size_t)e * BASIS);
    #pragma unroll
    for (int k0 = 0; k0 < 16; ++k0) {
        float4 xv = ea4[k0];
        #pragma unroll
        for (int c = 0; c < BASIS; ++c)
            dfeat[c] += xv.x * dfW[(4*k0+0)*64+c] + xv.y * dfW[(4*k0+1)*64+c]
                      + xv.z * dfW[(4*k0+2)*64+c] + xv.w * dfW[(4*k0+3)*64+c];
    }
    const float4* cf4 = (const float4*)(CF + (size_t)s * BASIS);
    float acc[BASIS];
    #pragma unroll
    for (int c = 0; c < BASIS; ++c) acc[c] = 0.0f;
    #pragma unroll
    for (int k0 = 0; k0 < 16; ++k0) {
        float4 a = cf4[k0];
        float x0 = a.x * dfeat[4*k0+0], x1 = a.y * dfeat[4*k0+1];
        float x2 = a.z * dfeat[4*k0+2], x3 = a.w * dfeat[4*k0+3];
        #pragma unroll
        for (int c = 0; c < BASIS; ++c)
            acc[c] += x0 * fcW[(4*k0+0)*64+c] + x1 * fcW[(4*k0+1)*64+c]
                    + x2 * fcW[(4*k0+2)*64+c] + x3 * fcW[(4*k0+3)*64+c];
    }
    float* crow = C + (size_t)d * BASIS;
    #pragma unroll
    for (int c = 0; c < BASIS; ++c) atomicAdd(&crow[c], fast_tanh(acc[c]));
}

// ---- readout (fallback): wave per node, W1 in LDS ----
__global__ __launch_bounds__(256) void k_readout2(const float* __restrict__ C,
        const float* __restrict__ W1, const float* __restrict__ b1,
        const float* __restrict__ W2, const float* __restrict__ b2,
        const int* __restrict__ batch, float* __restrict__ out) {
    __shared__ float w1[BASIS * HIDDEN_RO];   // 32 KB
    __shared__ float xbuf[4][64];
    int t = threadIdx.x;
    for (int i = t; i < BASIS * HIDDEN_RO; i += 256) w1[i] = W1[i];
    __syncthreads();
    int lane = t & 63, wv = t >> 6;
    float b1a = b1[lane], b1b = b1[64 + lane];
    float4 w2a = ((const float4*)W2)[lane];
    float4 w2b = ((const float4*)W2)[64 + lane];
    int wave = blockIdx.x * 4 + wv;
    int nw   = gridDim.x * 4;
    for (int n = wave; n < N_NODES; n += nw) {
        float x = C[(size_t)n * 64 + lane];
        xbuf[wv][lane] = x;
        __builtin_amdgcn_wave_barrier();
        const float4* xb = (const float4*)xbuf[wv];
        float sa = b1a, sb = b1b;
        #pragma unroll
        for (int k4 = 0; k4 < 16; ++k4) {
            float4 xv = xb[k4];
            const float* r0 = &w1[(4*k4 + 0) * HIDDEN_RO];
            const float* r1 = &w1[(4*k4 + 1) * HIDDEN_RO];
            const float* r2 = &w1[(4*k4 + 2) * HIDDEN_RO];
            const float* r3 = &w1[(4*k4 + 3) * HIDDEN_RO];
            sa += xv.x * r0[lane]      + xv.y * r1[lane]
                + xv.z * r2[lane]      + xv.w * r3[lane];
            sb += xv.x * r0[64 + lane] + xv.y * r1[64 + lane]
                + xv.z * r2[64 + lane] + xv.w * r3[64 + lane];
        }
        float ha = fast_tanh(sa), hb = fast_tanh(sb);
        float v0 = ha * w2a.x + hb * w2b.x;
        float v1 = ha * w2a.y + hb * w2b.y;
        float v2 = ha * w2a.z + hb * w2b.z;
        float v3 = ha * w2a.w + hb * w2b.w;
        #pragma unroll
        for (int ofs = 32; ofs >= 1; ofs >>= 1) {
            v0 += __shfl_down(v0, ofs, 64);
            v1 += __shfl_down(v1, ofs, 64);
            v2 += __shfl_down(v2, ofs, 64);
            v3 += __shfl_down(v3, ofs, 64);
        }
        if (lane == 0) {
            int g = batch[n];
            atomicAdd(&out[(size_t)g * 4 + 0], v0);
            atomicAdd(&out[(size_t)g * 4 + 1], v1);
            atomicAdd(&out[(size_t)g * 4 + 2], v2);
            atomicAdd(&out[(size_t)g * 4 + 3], v3);
        }
        __builtin_amdgcn_wave_barrier();
    }
}

// ---- readout (main): 16 nodes per wave, C@W1 via 3-term bf16-split MFMA ----
__global__ __launch_bounds__(256, 2) void k_readout3(const float* __restrict__ C,
        const s8* __restrict__ wimg, const float* __restrict__ b1,
        const float* __restrict__ W2, const float* __restrict__ b2,
        const int* __restrict__ batch, float* __restrict__ out) {
    __shared__ s8 LW[2048];   // 32 KB W1 image
    int t = threadIdx.x;
    for (int i = t; i < 2048; i += 256) LW[i] = wimg[i];
    __syncthreads();
    int lane = t & 63, wv = t >> 6, q = lane >> 4, c = lane & 15;
    float bias[8];
    #pragma unroll
    for (int g = 0; g < 8; ++g) bias[g] = b1[g*16 + c];
    f4 w2r[8];
    #pragma unroll
    for (int g = 0; g < 8; ++g) {
        float4 w4 = ((const float4*)W2)[g*16 + c];
        w2r[g][0] = w4.x; w2r[g][1] = w4.y; w2r[g][2] = w4.z; w2r[g][3] = w4.w;
    }
    float4 b2v = *(const float4*)b2;
    int chunks = (N_NODES + 15) >> 4;
    int wave = blockIdx.x * 4 + wv, nw = gridDim.x * 4;
    for (int ch = wave; ch < chunks; ch += nw) {
        int base = ch << 4;
        int row = base + c;
        bool valid = row < N_NODES;
        int r = valid ? row : 0;
        const float4* ip = (const float4*)(C + (size_t)r * 64);
        s8 ahi[2], alo[2];
        #pragma unroll
        for (int ks = 0; ks < 2; ++ks) {
            float4 a0 = ip[ks*8 + q*2 + 0];
            float4 a1 = ip[ks*8 + q*2 + 1];
            float xs[8] = {a0.x,a0.y,a0.z,a0.w, a1.x,a1.y,a1.z,a1.w};
            if (!valid) {
                #pragma unroll
                for (int j = 0; j < 8; ++j) xs[j] = 0.0f;
            }
            split8(xs, ahi[ks], alo[ks]);
        }
        f4 acc[8];
        #pragma unroll
        for (int g = 0; g < 8; ++g) acc[g] = splat4(bias[g]);
        #pragma unroll
        for (int ks = 0; ks < 2; ++ks)
            #pragma unroll
            for (int g = 0; g < 8; ++g) {
                s8 wh = LW[(ks*8 + g) * 64 + lane];
                s8 wl = LW[(16 + ks*8 + g) * 64 + lane];
                acc[g] = MFMA16(ahi[ks], wh, acc[g]);
                acc[g] = MFMA16(ahi[ks], wl, acc[g]);
                acc[g] = MFMA16(alo[ks], wh, acc[g]);
            }
        f4 v4[4];
        #pragma unroll
        for (int r2 = 0; r2 < 4; ++r2) v4[r2] = splat4(0.0f);
        #pragma unroll
        for (int g = 0; g < 8; ++g)
            #pragma unroll
            for (int r2 = 0; r2 < 4; ++r2) {
                float h = fast_tanh(acc[g][r2]);
                #pragma unroll
                for (int j = 0; j < 4; ++j) v4[r2][j] += h * w2r[g][j];
            }
        #pragma unroll
        for (int r2 = 0; r2 < 4; ++r2)
            #pragma unroll
            for (int j = 0; j < 4; ++j) {
                float x = v4[r2][j];
                x += __shfl_xor(x, 1, 64);
                x += __shfl_xor(x, 2, 64);
                x += __shfl_xor(x, 4, 64);
                x += __shfl_xor(x, 8, 64);
                v4[r2][j] = x;
            }
        if (c == 0) {
            #pragma unroll
            for (int r2 = 0; r2 < 4; ++r2) {
                int ro = base + q*4 + r2;
                if (ro < N_NODES) {
                    int g_id = batch[ro];
                    atomicAdd(&out[(size_t)g_id * 4 + 0], v4[r2][0] + b2v.x);
                    atomicAdd(&out[(size_t)g_id * 4 + 1], v4[r2][1] + b2v.y);
                    atomicAdd(&out[(size_t)g_id * 4 + 2], v4[r2][2] + b2v.z);
                    atomicAdd(&out[(size_t)g_id * 4 + 3], v4[r2][3] + b2v.w);
                }
            }
        }
    }
}

extern "C" void kernel_launch(void* const* d_in, const int* in_sizes, int n_in,
                              void* d_out, int out_size, void* d_ws, size_t ws_size,
                              hipStream_t stream) {
    // Z, edge_index, edge_attr, batch, embed, cfW, cfb, dfW, dfb, fcW, W1, b1, W2, b2
    const int*   Z     = (const int*)d_in[0];
    const int*   ei    = (const int*)d_in[1];
    const float* ea    = (const float*)d_in[2];
    const int*   batch = (const int*)d_in[3];
    const float* embed = (const float*)d_in[4];
    const float* cfW   = (const float*)d_in[5];
    const float* cfb   = (const float*)d_in[6];
    const float* dfW   = (const float*)d_in[7];
    const float* dfb   = (const float*)d_in[8];
    const float* fcW   = (const float*)d_in[9];
    const float* W1    = (const float*)d_in[10];
    const float* b1    = (const float*)d_in[11];
    const float* W2    = (const float*)d_in[12];
    const float* b2    = (const float*)d_in[13];
    const int* src = ei;
    const int* dst = ei + N_EDGES;
    float* out = (float*)d_out;

    const size_t bC = (size_t)N_NODES * BASIS * sizeof(float);   // 12.8 MB
    const size_t bE = (size_t)N_EDGES * sizeof(int);             // 3.2 MB
    const size_t bO = (size_t)(N_NODES + 1) * sizeof(int);
    const size_t bI = 1024 * sizeof(s8);                         // 16 KB per 64x64 W image
    char* p = (char*)d_ws;
    float* C      = (float*)p;  p += bC;
    float* CF     = (float*)p;  p += bC;
    int*   slotP  = (int*)p;    p += bE;
    int*   slotS  = (int*)p;    p += bE;
    int*   deg    = (int*)p;    p += bO;
    int*   off    = (int*)p;    p += bO;
    int*   cursor = (int*)p;    p += bO;
    p = (char*)(((uintptr_t)p + 255) & ~(uintptr_t)255);
    s8* imgDF = (s8*)p;  p += bI;
    s8* imgCF = (s8*)p;  p += bI;
    s8* imgFC = (s8*)p;  p += bI;
    s8* imgW1 = (s8*)p;  p += 2048 * sizeof(s8);                 // 32 KB readout W1 image
    int* bsum = (int*)p; p += 256 * sizeof(int);
    float* DF = (float*)p;
    const size_t need = (size_t)(p - (char*)d_ws) + (size_t)N_EDGES * BASIS * sizeof(float);
    const bool full = ws_size >= need;   // ~237 MB — held every prior round

    hipMemsetAsync(d_out, 0, (size_t)out_size * sizeof(float), stream);

    if (full) {
        hipMemsetAsync(deg, 0, bO, stream);
        k_init_hist<<<(N_NODES * BASIS + 255) / 256, 256, 0, stream>>>(Z, embed, C, dst, deg);
        k_packW<<<4, 256, 0, stream>>>(dfW, cfW, fcW, W1, imgDF, imgCF, imgFC, imgW1);
        k_scan1<<<NB_SCAN, 256, 0, stream>>>(deg, off, bsum);
        k_scan2<<<1, 256, 0, stream>>>(bsum);
        k_scan3<<<NB_SCAN, 256, 0, stream>>>(deg, off, bsum, cursor);
        k_fill<<<(N_EDGES + 255) / 256, 256, 0, stream>>>(src, dst, cursor, slotS, slotP);
        k_gemm64L<2><<<4096, 256, 0, stream>>>(ea, imgDF, dfb, slotP, DF, N_EDGES);
        for (int t = 0; t < T_ITERS; ++t) {
            k_gemm64L<0><<<800, 256, 0, stream>>>(C, imgCF, cfb, nullptr, CF, N_NODES);
            k_mp7<<<2048, 256, 0, stream>>>(CF, DF, imgFC, slotS, off, C);
        }
        k_readout3<<<1024, 256, 0, stream>>>(C, imgW1, b1, W2, b2, batch, out);
    } else {
        // minimal fallback: C + CF only (25.6 MB)
        k_init_hist<<<(N_NODES * BASIS + 255) / 256, 256, 0, stream>>>(Z, embed, C, dst, (int*)CF);
        for (int t = 0; t < T_ITERS; ++t) {
            k_gemm64_fb<<<(N_NODES + 255) / 256, 256, 0, stream>>>(C, cfW, cfb, CF, N_NODES);
            k_edge_fb<<<(N_EDGES + 255) / 256, 256, 0, stream>>>(CF, ea, dfW, dfb, fcW, src, dst, C);
        }
        k_readout2<<<512, 256, 0, stream>>>(C, W1, b1, W2, b2, batch, out);
    }
}

// Round 8
// 805.803 us; speedup vs baseline: 1.0901x; 1.0901x over previous
//
#include <hip/hip_runtime.h>
#include <math.h>

#define N_NODES   50000
#define N_EDGES   800000
#define BASIS     64
#define HIDDEN_RO 128
#define N_GRAPHS  512
#define T_ITERS   3
#define NB_SCAN   ((N_NODES + 255) / 256)   // 196

typedef short s8 __attribute__((ext_vector_type(8)));   // 8 bf16 in 4 VGPRs
typedef float f4 __attribute__((ext_vector_type(4)));

#define MFMA16(a, b, c) __builtin_amdgcn_mfma_f32_16x16x32_bf16(a, b, c, 0, 0, 0)

// tanh(x) = 1 - 2/(e^{2x}+1); overflow-safe both directions, tanh(0)=0 exactly.
__device__ __forceinline__ float fast_tanh(float x) {
    float e = __expf(2.0f * x);
    return 1.0f - 2.0f / (e + 1.0f);
}

__device__ __forceinline__ f4 splat4(float x) { f4 v; v[0]=x; v[1]=x; v[2]=x; v[3]=x; return v; }

// Split 8 fp32 into bf16 hi (truncation) + bf16 lo (residual) — proven, absmax 0.0625.
__device__ __forceinline__ void split8(const float* x, s8& hi, s8& lo) {
    union { unsigned a[4]; s8 v; } H, L;
    #pragma unroll
    for (int j = 0; j < 4; ++j) {
        float e0 = x[2*j], e1 = x[2*j+1];
        unsigned u0 = __float_as_uint(e0), u1 = __float_as_uint(e1);
        H.a[j] = (u0 >> 16) | (u1 & 0xFFFF0000u);
        float l0 = e0 - __uint_as_float(u0 & 0xFFFF0000u);   // exact
        float l1 = e1 - __uint_as_float(u1 & 0xFFFF0000u);
        L.a[j] = (__float_as_uint(l0) >> 16) | (__float_as_uint(l1) & 0xFFFF0000u);
    }
    hi = H.v; lo = L.v;
}

// ---- W frag pre-pack: img[f*64+lane], f = ks*4+g (hi), 8+ks*4+g (lo); 16 KB/matrix ----
__device__ __forceinline__ void packW_dev(const float* __restrict__ W, s8* __restrict__ img, int t) {
    int lane = t & 63, q = lane >> 4, c = lane & 15;
    int f0 = (t >> 6) * 2;
    #pragma unroll
    for (int f = f0; f < f0 + 2; ++f) {          // f in 0..7 across the 4 sub-groups
        int ks = f >> 2, g = f & 3;
        float tv[8];
        #pragma unroll
        for (int j = 0; j < 8; ++j)
            tv[j] = W[(ks*32 + q*8 + j) * 64 + g*16 + c];
        s8 hi, lo;
        split8(tv, hi, lo);
        img[f * 64 + lane]       = hi;
        img[(8 + f) * 64 + lane] = lo;
    }
}

// W1 readout pack: 64x128 -> 16 hi frags (f = ks*8+g) + 16 lo frags; 32 KB image
__device__ __forceinline__ void packW1_dev(const float* __restrict__ W, s8* __restrict__ img, int t) {
    int lane = t & 63, q = lane >> 4, c = lane & 15;
    int f0 = (t >> 6) * 4;
    #pragma unroll
    for (int f = f0; f < f0 + 4; ++f) {          // f in 0..15 across the 4 waves
        int ks = f >> 3, g = f & 7;
        float tv[8];
        #pragma unroll
        for (int j = 0; j < 8; ++j)
            tv[j] = W[(ks*32 + q*8 + j) * HIDDEN_RO + g*16 + c];
        s8 hi, lo;
        split8(tv, hi, lo);
        img[f * 64 + lane]        = hi;
        img[(16 + f) * 64 + lane] = lo;
    }
}

__global__ void k_packW(const float* __restrict__ W0, const float* __restrict__ W1m,
                        const float* __restrict__ W2m, const float* __restrict__ W1ro,
                        s8* __restrict__ i0, s8* __restrict__ i1, s8* __restrict__ i2,
                        s8* __restrict__ i3) {
    int b = blockIdx.x, t = threadIdx.x;
    if (b == 0) packW_dev(W0, i0, t);
    else if (b == 1) packW_dev(W1m, i1, t);
    else if (b == 2) packW_dev(W2m, i2, t);
    else packW1_dev(W1ro, i3, t);
}

// C init + degree histogram fused
__global__ void k_init_hist(const int* __restrict__ Z, const float* __restrict__ embed,
                            float* __restrict__ C, const int* __restrict__ dst,
                            int* __restrict__ deg) {
    int i = blockIdx.x * blockDim.x + threadIdx.x;
    if (i < N_NODES * BASIS) { int n = i >> 6, c = i & 63; C[i] = embed[Z[n] * 64 + c]; }
    if (i < N_EDGES) atomicAdd(&deg[dst[i]], 1);
}

// ---- hierarchical scan: 196-block local scan -> 1-block scan of block sums -> add-back ----
__global__ void k_scan1(const int* __restrict__ deg, int* __restrict__ off,
                        int* __restrict__ bsum) {
    __shared__ int ws[4];
    int b = blockIdx.x, t = threadIdx.x, lane = t & 63, w = t >> 6;
    int i = b * 256 + t;
    int v = (i < N_NODES) ? deg[i] : 0;
    int s = v;
    #pragma unroll
    for (int ofs = 1; ofs < 64; ofs <<= 1) {
        int tmp = __shfl_up(s, ofs, 64);
        if (lane >= ofs) s += tmp;
    }
    if (lane == 63) ws[w] = s;
    __syncthreads();
    if (t == 0) {
        int a = 0;
        #pragma unroll
        for (int k = 0; k < 4; ++k) { int x = ws[k]; ws[k] = a; a += x; }
        bsum[b] = a;
    }
    __syncthreads();
    int excl = ws[w] + s - v;
    if (i < N_NODES) off[i] = excl;
}

__global__ void k_scan2(int* __restrict__ bsum) {   // 1 block, 256 threads; NB_SCAN <= 256
    __shared__ int ws[4];
    int t = threadIdx.x, lane = t & 63, w = t >> 6;
    int v = (t < NB_SCAN) ? bsum[t] : 0;
    int s = v;
    #pragma unroll
    for (int ofs = 1; ofs < 64; ofs <<= 1) {
        int tmp = __shfl_up(s, ofs, 64);
        if (lane >= ofs) s += tmp;
    }
    if (lane == 63) ws[w] = s;
    __syncthreads();
    if (t == 0) {
        int a = 0;
        #pragma unroll
        for (int k = 0; k < 4; ++k) { int x = ws[k]; ws[k] = a; a += x; }
    }
    __syncthreads();
    int excl = ws[w] + s - v;
    if (t < NB_SCAN) bsum[t] = excl;
}

__global__ void k_scan3(const int* __restrict__ deg, int* __restrict__ off,
                        const int* __restrict__ bsum, int* __restrict__ cursor) {
    int b = blockIdx.x, i = b * 256 + threadIdx.x;
    if (i < N_NODES) {
        int val = off[i] + bsum[b];
        off[i] = val;
        cursor[i] = val;
        if (i == N_NODES - 1) off[N_NODES] = val + deg[i];
    }
}

// slot_sn[p] = (dst<<16)|src (both < 50000 < 2^16), slot_p[e]=p (edge->slot inverse)
__global__ void k_fill(const int* __restrict__ src, const int* __restrict__ dst,
                       int* __restrict__ cursor, unsigned* __restrict__ slot_sn,
                       int* __restrict__ slot_p) {
    int e = blockIdx.x * blockDim.x + threadIdx.x;
    if (e < N_EDGES) {
        int d = dst[e], s = src[e];
        int p = atomicAdd(&cursor[d], 1);
        slot_sn[p] = ((unsigned)d << 16) | (unsigned)s;
        slot_p[e] = p;
    }
}

// ---- generic 64x64 linear via MFMA, W frags from LDS ----
// MODE 0: out[r,:] = in[r,:]@W + b, sequential rows in and out.
// MODE 2: out[map[r],:] = in[r,:]@W + b — sequential coalesced READ, scattered write.
template <int MODE>
__global__ __launch_bounds__(256, 4) void k_gemm64L(const float* __restrict__ in,
        const s8* __restrict__ wimg, const float* __restrict__ b,
        const int* __restrict__ map, float* __restrict__ out, int rows) {
    __shared__ s8 LW[1024];   // 16 KB
    int t = threadIdx.x;
    for (int i = t; i < 1024; i += 256) LW[i] = wimg[i];
    __syncthreads();
    int lane = t & 63, wv = t >> 6, q = lane >> 4, c = lane & 15;
    float bias[4];
    #pragma unroll
    for (int g = 0; g < 4; ++g) bias[g] = b[g*16 + c];
    int chunks = (rows + 15) >> 4;
    int wave = blockIdx.x * 4 + wv, nw = gridDim.x * 4;
    for (int ch = wave; ch < chunks; ch += nw) {
        int base = ch << 4;
        int row = base + c;
        bool valid = row < rows;
        int r = valid ? row : 0;
        const float4* ip = (const float4*)(in + (size_t)r * 64);
        s8 ahi[2], alo[2];
        #pragma unroll
        for (int ks = 0; ks < 2; ++ks) {
            float4 a0 = ip[ks*8 + q*2 + 0];
            float4 a1 = ip[ks*8 + q*2 + 1];
            float xs[8] = {a0.x,a0.y,a0.z,a0.w, a1.x,a1.y,a1.z,a1.w};
            if (!valid) {
                #pragma unroll
                for (int j = 0; j < 8; ++j) xs[j] = 0.0f;
            }
            split8(xs, ahi[ks], alo[ks]);
        }
        int orow[4];
        #pragma unroll
        for (int r2 = 0; r2 < 4; ++r2) {
            int ro = base + q*4 + r2;
            if (ro >= rows) ro = rows - 1;
            orow[r2] = (MODE == 2) ? map[ro] : ro;
        }
        f4 acc[4];
        #pragma unroll
        for (int g = 0; g < 4; ++g) acc[g] = splat4(bias[g]);
        #pragma unroll
        for (int ks = 0; ks < 2; ++ks)
            #pragma unroll
            for (int g = 0; g < 4; ++g) {
                s8 wh = LW[(ks*4 + g) * 64 + lane];
                s8 wl = LW[(8 + ks*4 + g) * 64 + lane];
                acc[g] = MFMA16(ahi[ks], wh, acc[g]);
                acc[g] = MFMA16(ahi[ks], wl, acc[g]);
                acc[g] = MFMA16(alo[ks], wh, acc[g]);
            }
        #pragma unroll
        for (int g = 0; g < 4; ++g)
            #pragma unroll
            for (int r2 = 0; r2 < 4; ++r2) {
                if (base + q*4 + r2 < rows)
                    out[(size_t)orow[r2] * 64 + g*16 + c] = acc[g][r2];
            }
    }
}

// ---- fused message+aggregate, slot-order segmented (k_mp8) ----
// Waves grid-stride over global 16-slot chunks (800000/16 = 50000, exact): no padding
// (was ~32% of chunks), no off[] loads, DF reads fully sequential. CSR slots are
// node-ordered, so each chunk holds 1-3 contiguous node segments; a wave-uniform
// ballot/ffs loop does a segmented quad-reduce and one atomicAdd per lane per segment.
// Arithmetic per edge identical to the verified mp5 path (split8/MFMA/tanh).
__global__ __launch_bounds__(256, 4) void k_mp8(const float* __restrict__ CF,
        const float* __restrict__ DF, const s8* __restrict__ wimg,
        const unsigned* __restrict__ slot_sn, float* __restrict__ C) {
    __shared__ s8 LW[1024];   // 16 KB
    int t = threadIdx.x;
    for (int i = t; i < 1024; i += 256) LW[i] = wimg[i];
    __syncthreads();
    int lane = t & 63, wv = t >> 6, q = lane >> 4, c = lane & 15;
    int wave = blockIdx.x * 4 + wv, nw = gridDim.x * 4;
    const int NCH = N_EDGES >> 4;   // 50000
    for (int ch = wave; ch < NCH; ch += nw) {
        int slot = (ch << 4) + c;
        unsigned sn = slot_sn[slot];
        int sA  = (int)(sn & 0xFFFFu);   // src node (CF gather row)
        int myn = (int)(sn >> 16);       // dst node of row c (non-decreasing in slot)
        const float4* dp = (const float4*)(DF + (size_t)slot * 64);  // sequential stream
        float4 d0 = dp[q*2],     d1 = dp[q*2 + 1];
        float4 d2 = dp[8 + q*2], d3 = dp[8 + q*2 + 1];
        const float4* cp = (const float4*)(CF + (size_t)sA * 64);    // gather (L2/L3 hot)
        float4 c0 = cp[q*2],     c1 = cp[q*2 + 1];
        float4 c2 = cp[8 + q*2], c3 = cp[8 + q*2 + 1];
        s8 ahi[2], alo[2];
        {
            float xs[8] = {c0.x*d0.x, c0.y*d0.y, c0.z*d0.z, c0.w*d0.w,
                           c1.x*d1.x, c1.y*d1.y, c1.z*d1.z, c1.w*d1.w};
            split8(xs, ahi[0], alo[0]);
            float ys[8] = {c2.x*d2.x, c2.y*d2.y, c2.z*d2.z, c2.w*d2.w,
                           c3.x*d3.x, c3.y*d3.y, c3.z*d3.z, c3.w*d3.w};
            split8(ys, ahi[1], alo[1]);
        }
        f4 d[4];
        #pragma unroll
        for (int g = 0; g < 4; ++g) d[g] = splat4(0.0f);
        #pragma unroll
        for (int ks = 0; ks < 2; ++ks)
            #pragma unroll
            for (int g = 0; g < 4; ++g) {
                s8 wh = LW[(ks*4 + g) * 64 + lane];
                s8 wl = LW[(8 + ks*4 + g) * 64 + lane];
                d[g] = MFMA16(ahi[ks], wh, d[g]);
                d[g] = MFMA16(ahi[ks], wl, d[g]);
                d[g] = MFMA16(alo[ks], wh, d[g]);
            }
        // tanh in place: d[g][r2] = tanh(msg[row=q*4+r2][col=g*16+c])
        #pragma unroll
        for (int g = 0; g < 4; ++g)
            #pragma unroll
            for (int r2 = 0; r2 < 4; ++r2)
                d[g][r2] = fast_tanh(d[g][r2]);
        // owner node of each of my 4 output rows (rows = q*4+r2; holder lane = row index)
        int nrow[4];
        #pragma unroll
        for (int r2 = 0; r2 < 4; ++r2) nrow[r2] = __shfl(myn, q*4 + r2, 64);
        // wave-uniform segment loop (1-3 iterations typical)
        int segN = __shfl(myn, 0, 64);
        while (true) {
            float s0 = 0.f, s1 = 0.f, s2 = 0.f, s3 = 0.f;
            #pragma unroll
            for (int r2 = 0; r2 < 4; ++r2) {
                bool in = (nrow[r2] == segN);
                s0 += in ? d[0][r2] : 0.0f;
                s1 += in ? d[1][r2] : 0.0f;
                s2 += in ? d[2][r2] : 0.0f;
                s3 += in ? d[3][r2] : 0.0f;
            }
            s0 += __shfl_xor(s0, 16, 64); s0 += __shfl_xor(s0, 32, 64);
            s1 += __shfl_xor(s1, 16, 64); s1 += __shfl_xor(s1, 32, 64);
            s2 += __shfl_xor(s2, 16, 64); s2 += __shfl_xor(s2, 32, 64);
            s3 += __shfl_xor(s3, 16, 64); s3 += __shfl_xor(s3, 32, 64);
            float v = (q == 0) ? s0 : (q == 1) ? s1 : (q == 2) ? s2 : s3;
            atomicAdd(&C[(size_t)segN * 64 + lane], v);
            unsigned long long m = __ballot((lane < 16) && (myn > segN));
            if (m == 0ull) break;
            segN = __shfl(myn, __ffsll((unsigned long long)m) - 1, 64);
        }
    }
}

// ---- fallback path (ws too small; never expected — kept for safety) ----
__global__ __launch_bounds__(256) void k_gemm64_fb(const float* __restrict__ in,
        const float* __restrict__ W, const float* __restrict__ b,
        float* __restrict__ out, int rows) {
    int r = blockIdx.x * blockDim.x + threadIdx.x;
    if (r >= rows) return;
    float acc[BASIS];
    #pragma unroll
    for (int c = 0; c < BASIS; ++c) acc[c] = b[c];
    const float4* in4 = (const float4*)(in + (size_t)r * BASIS);
    #pragma unroll 1
    for (int k0 = 0; k0 < 16; ++k0) {
        float4 xv = in4[k0];
        #pragma unroll
        for (int c = 0; c < BASIS; ++c)
            acc[c] += xv.x * W[(4*k0+0)*64+c] + xv.y * W[(4*k0+1)*64+c]
                    + xv.z * W[(4*k0+2)*64+c] + xv.w * W[(4*k0+3)*64+c];
    }
    #pragma unroll
    for (int c = 0; c < BASIS; ++c) out[(size_t)r * BASIS + c] = acc[c];
}
__global__ __launch_bounds__(256) void k_edge_fb(const float* __restrict__ CF,
        const float* __restrict__ ea, const float* __restrict__ dfW,
        const float* __restrict__ dfb, const float* __restrict__ fcW,
        const int* __restrict__ src, const int* __restrict__ dst,
        float* __restrict__ C) {
    int e = blockIdx.x * blockDim.x + threadIdx.x;
    if (e >= N_EDGES) return;
    int s = src[e], d = dst[e];
    float dfeat[BASIS];
    #pragma unroll
    for (int c = 0; c < BASIS; ++c) dfeat[c] = dfb[c];
    const float4* ea4 = (const float4*)(ea + (size_t)e * BASIS);
    #pragma unroll
    for (int k0 = 0; k0 < 16; ++k0) {
        float4 xv = ea4[k0];
        #pragma unroll
        for (int c = 0; c < BASIS; ++c)
            dfeat[c] += xv.x * dfW[(4*k0+0)*64+c] + xv.y * dfW[(4*k0+1)*64+c]
                      + xv.z * dfW[(4*k0+2)*64+c] + xv.w * dfW[(4*k0+3)*64+c];
    }
    const float4* cf4 = (const float4*)(CF + (size_t)s * BASIS);
    float acc[BASIS];
    #pragma unroll
    for (int c = 0; c < BASIS; ++c) acc[c] = 0.0f;
    #pragma unroll
    for (int k0 = 0; k0 < 16; ++k0) {
        float4 a = cf4[k0];
        float x0 = a.x * dfeat[4*k0+0], x1 = a.y * dfeat[4*k0+1];
        float x2 = a.z * dfeat[4*k0+2], x3 = a.w * dfeat[4*k0+3];
        #pragma unroll
        for (int c = 0; c < BASIS; ++c)
            acc[c] += x0 * fcW[(4*k0+0)*64+c] + x1 * fcW[(4*k0+1)*64+c]
                    + x2 * fcW[(4*k0+2)*64+c] + x3 * fcW[(4*k0+3)*64+c];
    }
    float* crow = C + (size_t)d * BASIS;
    #pragma unroll
    for (int c = 0; c < BASIS; ++c) atomicAdd(&crow[c], fast_tanh(acc[c]));
}

// ---- readout (fallback): wave per node, W1 in LDS ----
__global__ __launch_bounds__(256) void k_readout2(const float* __restrict__ C,
        const float* __restrict__ W1, const float* __restrict__ b1,
        const float* __restrict__ W2, const float* __restrict__ b2,
        const int* __restrict__ batch, float* __restrict__ out) {
    __shared__ float w1[BASIS * HIDDEN_RO];   // 32 KB
    __shared__ float xbuf[4][64];
    int t = threadIdx.x;
    for (int i = t; i < BASIS * HIDDEN_RO; i += 256) w1[i] = W1[i];
    __syncthreads();
    int lane = t & 63, wv = t >> 6;
    float b1a = b1[lane], b1b = b1[64 + lane];
    float4 w2a = ((const float4*)W2)[lane];
    float4 w2b = ((const float4*)W2)[64 + lane];
    int wave = blockIdx.x * 4 + wv;
    int nw   = gridDim.x * 4;
    for (int n = wave; n < N_NODES; n += nw) {
        float x = C[(size_t)n * 64 + lane];
        xbuf[wv][lane] = x;
        __builtin_amdgcn_wave_barrier();
        const float4* xb = (const float4*)xbuf[wv];
        float sa = b1a, sb = b1b;
        #pragma unroll
        for (int k4 = 0; k4 < 16; ++k4) {
            float4 xv = xb[k4];
            const float* r0 = &w1[(4*k4 + 0) * HIDDEN_RO];
            const float* r1 = &w1[(4*k4 + 1) * HIDDEN_RO];
            const float* r2 = &w1[(4*k4 + 2) * HIDDEN_RO];
            const float* r3 = &w1[(4*k4 + 3) * HIDDEN_RO];
            sa += xv.x * r0[lane]      + xv.y * r1[lane]
                + xv.z * r2[lane]      + xv.w * r3[lane];
            sb += xv.x * r0[64 + lane] + xv.y * r1[64 + lane]
                + xv.z * r2[64 + lane] + xv.w * r3[64 + lane];
        }
        float ha = fast_tanh(sa), hb = fast_tanh(sb);
        float v0 = ha * w2a.x + hb * w2b.x;
        float v1 = ha * w2a.y + hb * w2b.y;
        float v2 = ha * w2a.z + hb * w2b.z;
        float v3 = ha * w2a.w + hb * w2b.w;
        #pragma unroll
        for (int ofs = 32; ofs >= 1; ofs >>= 1) {
            v0 += __shfl_down(v0, ofs, 64);
            v1 += __shfl_down(v1, ofs, 64);
            v2 += __shfl_down(v2, ofs, 64);
            v3 += __shfl_down(v3, ofs, 64);
        }
        if (lane == 0) {
            int g = batch[n];
            atomicAdd(&out[(size_t)g * 4 + 0], v0);
            atomicAdd(&out[(size_t)g * 4 + 1], v1);
            atomicAdd(&out[(size_t)g * 4 + 2], v2);
            atomicAdd(&out[(size_t)g * 4 + 3], v3);
        }
        __builtin_amdgcn_wave_barrier();
    }
}

// ---- readout (main): 16 nodes per wave, C@W1 via 3-term bf16-split MFMA ----
__global__ __launch_bounds__(256, 2) void k_readout3(const float* __restrict__ C,
        const s8* __restrict__ wimg, const float* __restrict__ b1,
        const float* __restrict__ W2, const float* __restrict__ b2,
        const int* __restrict__ batch, float* __restrict__ out) {
    __shared__ s8 LW[2048];   // 32 KB W1 image
    int t = threadIdx.x;
    for (int i = t; i < 2048; i += 256) LW[i] = wimg[i];
    __syncthreads();
    int lane = t & 63, wv = t >> 6, q = lane >> 4, c = lane & 15;
    float bias[8];
    #pragma unroll
    for (int g = 0; g < 8; ++g) bias[g] = b1[g*16 + c];
    f4 w2r[8];
    #pragma unroll
    for (int g = 0; g < 8; ++g) {
        float4 w4 = ((const float4*)W2)[g*16 + c];
        w2r[g][0] = w4.x; w2r[g][1] = w4.y; w2r[g][2] = w4.z; w2r[g][3] = w4.w;
    }
    float4 b2v = *(const float4*)b2;
    int chunks = (N_NODES + 15) >> 4;
    int wave = blockIdx.x * 4 + wv, nw = gridDim.x * 4;
    for (int ch = wave; ch < chunks; ch += nw) {
        int base = ch << 4;
        int row = base + c;
        bool valid = row < N_NODES;
        int r = valid ? row : 0;
        const float4* ip = (const float4*)(C + (size_t)r * 64);
        s8 ahi[2], alo[2];
        #pragma unroll
        for (int ks = 0; ks < 2; ++ks) {
            float4 a0 = ip[ks*8 + q*2 + 0];
            float4 a1 = ip[ks*8 + q*2 + 1];
            float xs[8] = {a0.x,a0.y,a0.z,a0.w, a1.x,a1.y,a1.z,a1.w};
            if (!valid) {
                #pragma unroll
                for (int j = 0; j < 8; ++j) xs[j] = 0.0f;
            }
            split8(xs, ahi[ks], alo[ks]);
        }
        f4 acc[8];
        #pragma unroll
        for (int g = 0; g < 8; ++g) acc[g] = splat4(bias[g]);
        #pragma unroll
        for (int ks = 0; ks < 2; ++ks)
            #pragma unroll
            for (int g = 0; g < 8; ++g) {
                s8 wh = LW[(ks*8 + g) * 64 + lane];
                s8 wl = LW[(16 + ks*8 + g) * 64 + lane];
                acc[g] = MFMA16(ahi[ks], wh, acc[g]);
                acc[g] = MFMA16(ahi[ks], wl, acc[g]);
                acc[g] = MFMA16(alo[ks], wh, acc[g]);
            }
        f4 v4[4];
        #pragma unroll
        for (int r2 = 0; r2 < 4; ++r2) v4[r2] = splat4(0.0f);
        #pragma unroll
        for (int g = 0; g < 8; ++g)
            #pragma unroll
            for (int r2 = 0; r2 < 4; ++r2) {
                float h = fast_tanh(acc[g][r2]);
                #pragma unroll
                for (int j = 0; j < 4; ++j) v4[r2][j] += h * w2r[g][j];
            }
        #pragma unroll
        for (int r2 = 0; r2 < 4; ++r2)
            #pragma unroll
            for (int j = 0; j < 4; ++j) {
                float x = v4[r2][j];
                x += __shfl_xor(x, 1, 64);
                x += __shfl_xor(x, 2, 64);
                x += __shfl_xor(x, 4, 64);
                x += __shfl_xor(x, 8, 64);
                v4[r2][j] = x;
            }
        if (c == 0) {
            #pragma unroll
            for (int r2 = 0; r2 < 4; ++r2) {
                int ro = base + q*4 + r2;
                if (ro < N_NODES) {
                    int g_id = batch[ro];
                    atomicAdd(&out[(size_t)g_id * 4 + 0], v4[r2][0] + b2v.x);
                    atomicAdd(&out[(size_t)g_id * 4 + 1], v4[r2][1] + b2v.y);
                    atomicAdd(&out[(size_t)g_id * 4 + 2], v4[r2][2] + b2v.z);
                    atomicAdd(&out[(size_t)g_id * 4 + 3], v4[r2][3] + b2v.w);
                }
            }
        }
    }
}

extern "C" void kernel_launch(void* const* d_in, const int* in_sizes, int n_in,
                              void* d_out, int out_size, void* d_ws, size_t ws_size,
                              hipStream_t stream) {
    // Z, edge_index, edge_attr, batch, embed, cfW, cfb, dfW, dfb, fcW, W1, b1, W2, b2
    const int*   Z     = (const int*)d_in[0];
    const int*   ei    = (const int*)d_in[1];
    const float* ea    = (const float*)d_in[2];
    const int*   batch = (const int*)d_in[3];
    const float* embed = (const float*)d_in[4];
    const float* cfW   = (const float*)d_in[5];
    const float* cfb   = (const float*)d_in[6];
    const float* dfW   = (const float*)d_in[7];
    const float* dfb   = (const float*)d_in[8];
    const float* fcW   = (const float*)d_in[9];
    const float* W1    = (const float*)d_in[10];
    const float* b1    = (const float*)d_in[11];
    const float* W2    = (const float*)d_in[12];
    const float* b2    = (const float*)d_in[13];
    const int* src = ei;
    const int* dst = ei + N_EDGES;
    float* out = (float*)d_out;

    const size_t bC = (size_t)N_NODES * BASIS * sizeof(float);   // 12.8 MB
    const size_t bE = (size_t)N_EDGES * sizeof(int);             // 3.2 MB
    const size_t bO = (size_t)(N_NODES + 1) * sizeof(int);
    const size_t bI = 1024 * sizeof(s8);                         // 16 KB per 64x64 W image
    char* p = (char*)d_ws;
    float* C      = (float*)p;  p += bC;
    float* CF     = (float*)p;  p += bC;
    int*   slotP  = (int*)p;    p += bE;
    unsigned* slotSN = (unsigned*)p; p += bE;
    int*   deg    = (int*)p;    p += bO;
    int*   off    = (int*)p;    p += bO;
    int*   cursor = (int*)p;    p += bO;
    p = (char*)(((uintptr_t)p + 255) & ~(uintptr_t)255);
    s8* imgDF = (s8*)p;  p += bI;
    s8* imgCF = (s8*)p;  p += bI;
    s8* imgFC = (s8*)p;  p += bI;
    s8* imgW1 = (s8*)p;  p += 2048 * sizeof(s8);                 // 32 KB readout W1 image
    int* bsum = (int*)p; p += 256 * sizeof(int);
    float* DF = (float*)p;
    const size_t need = (size_t)(p - (char*)d_ws) + (size_t)N_EDGES * BASIS * sizeof(float);
    const bool full = ws_size >= need;   // ~237 MB — held every prior round

    hipMemsetAsync(d_out, 0, (size_t)out_size * sizeof(float), stream);

    if (full) {
        hipMemsetAsync(deg, 0, bO, stream);
        k_init_hist<<<(N_NODES * BASIS + 255) / 256, 256, 0, stream>>>(Z, embed, C, dst, deg);
        k_packW<<<4, 256, 0, stream>>>(dfW, cfW, fcW, W1, imgDF, imgCF, imgFC, imgW1);
        k_scan1<<<NB_SCAN, 256, 0, stream>>>(deg, off, bsum);
        k_scan2<<<1, 256, 0, stream>>>(bsum);
        k_scan3<<<NB_SCAN, 256, 0, stream>>>(deg, off, bsum, cursor);
        k_fill<<<(N_EDGES + 255) / 256, 256, 0, stream>>>(src, dst, cursor, slotSN, slotP);
        k_gemm64L<2><<<4096, 256, 0, stream>>>(ea, imgDF, dfb, slotP, DF, N_EDGES);
        for (int t = 0; t < T_ITERS; ++t) {
            k_gemm64L<0><<<800, 256, 0, stream>>>(C, imgCF, cfb, nullptr, CF, N_NODES);
            k_mp8<<<2048, 256, 0, stream>>>(CF, DF, imgFC, slotSN, C);
        }
        k_readout3<<<1024, 256, 0, stream>>>(C, imgW1, b1, W2, b2, batch, out);
    } else {
        // minimal fallback: C + CF only (25.6 MB)
        k_init_hist<<<(N_NODES * BASIS + 255) / 256, 256, 0, stream>>>(Z, embed, C, dst, (int*)CF);
        for (int t = 0; t < T_ITERS; ++t) {
            k_gemm64_fb<<<(N_NODES + 255) / 256, 256, 0, stream>>>(C, cfW, cfb, CF, N_NODES);
            k_edge_fb<<<(N_EDGES + 255) / 256, 256, 0, stream>>>(CF, ea, dfW, dfb, fcW, src, dst, C);
        }
        k_readout2<<<512, 256, 0, stream>>>(C, W1, b1, W2, b2, batch, out);
    }
}